// Round 5
// baseline (377.954 us; speedup 1.0000x reference)
//
#include <hip/hip_runtime.h>

// SeriesDecomp: trend = mean of moving averages (k = 7, 25, 49, replicate pad),
// residual = x - trend.  x: [32, 4096, 512] fp32.
// d_out = [residual | trend], each B*L*C floats.
//
// R5: R4 (register FIFO, compile-time &63 indices) at 159 us ~= 84% of the
// mixed-BW ceiling. This round: VEC=2 (float2 per lane -> dwordx2, halves
// VMEM instruction count), CHUNK=1024 (read halo 12.3% -> 6.2%), 128-thread
// blocks -> grid 256 = exactly 1 block/CU. FIFO = 64 x float2 = 128 VGPR,
// still fully-unrolled constant-indexed so SROA keeps it in registers
// (launch_bounds(128,2) caps regalloc at 256 VGPR -> headroom, no spill).
// MLP: 4 waves/CU x ~14 outstanding x 512B ~= 29 KB in flight >> 9.2 KB
// BW-latency product -> BW-saturated despite 1 wave/SIMD.

namespace {
constexpr int B = 32;
constexpr int L = 4096;
constexpr int C = 512;
constexpr int C2 = C / 2;          // 256 float2 channel-pairs per row
constexpr int CPB = 128;           // threads per block = float2 pairs per block
constexpr int CHUNK = 1024;        // time steps per block
constexpr int BODY = 64;           // unrolled steps == FIFO depth
constexpr int NB = CHUNK / BODY;   // 16 outer iterations
constexpr int PF = 14;             // prefetch beyond t+25; span 50+14 = 64 exact

__global__ __launch_bounds__(CPB, 2) void series_decomp_kernel(
    const float2* __restrict__ x,
    float2* __restrict__ res,
    float2* __restrict__ trend) {
  const int tid = threadIdx.x;     // 0..127
  const int chunk = blockIdx.x;    // 0..3
  const int chg = blockIdx.y;      // 0..1 (which half of the 512 channels)
  const int b = blockIdx.z;        // 0..31
  const int t0 = chunk * CHUNK;    // multiple of 1024 -> t0 & 63 == 0
  const int g2 = chg * CPB + tid;  // float2 group 0..255

  const size_t colbase = (size_t)b * L * C2 + g2;
  const float2* xp = x + colbase;

  float2 fifo[BODY];  // slot (r & 63) holds x[min(max(r,0),L-1)] (replicate)

  // Prologue: virtual rows t0-24 .. t0+38 -> slots (k+40)&63, k = 0..62.
  // Slot 39 is first written by step i=0 of the main body.
#pragma unroll
  for (int k = 0; k < BODY - 1; ++k) {
    int r = t0 - 24 + k;
    r = min(max(r, 0), L - 1);
    fifo[(k + 40) & 63] = xp[(size_t)r * C2];
  }

  // Initial window sums centered at t0 (virtual rows t0-24 .. t0+24).
  float sx7 = 0.f, sy7 = 0.f, sx25 = 0.f, sy25 = 0.f, sx49 = 0.f, sy49 = 0.f;
#pragma unroll
  for (int k = 0; k < 49; ++k) {
    float2 v = fifo[(k + 40) & 63];
    sx49 += v.x; sy49 += v.y;
    if (k >= 12 && k <= 36) { sx25 += v.x; sy25 += v.y; }  // t0-12..t0+12
    if (k >= 21 && k <= 27) { sx7  += v.x; sy7  += v.y; }  // t0-3 ..t0+3
  }

  // Folded coefficients: trend = s7/(7*3) + s25/(25*3) + s49/(49*3).
  const float c7 = 1.f / 21.f, c25 = 1.f / 75.f, c49 = 1.f / 147.f;

  float2* rp = res + colbase + (size_t)t0 * C2;
  float2* tp = trend + colbase + (size_t)t0 * C2;

  for (int g = 0; g < NB; ++g) {
    const int tb = t0 + g * BODY;  // tb & 63 == 0 -> slot(row r) = r & 63
#pragma unroll
    for (int i = 0; i < BODY; ++i) {
      // Prefetch virtual row tb+i+39 into slot (i+39)&63. Old content (row
      // t-25) was last read as d49 at step i-1 (WAR-safe); new value is first
      // read as a49 at step i+14 -> 14-step latency cover (PF=14).
      {
        int r = min(tb + i + 25 + PF, L - 1);   // r >= 39 > 0 always
        fifo[(i + 25 + PF) & 63] = xp[(size_t)r * C2];
      }

      float2 xv  = fifo[i];               // x[t]
      float2 a7  = fifo[(i + 4)  & 63];   // x[t+4]
      float2 d7  = fifo[(i + 61) & 63];   // x[t-3]
      float2 a25 = fifo[(i + 13) & 63];   // x[t+13]
      float2 d25 = fifo[(i + 52) & 63];   // x[t-12]
      float2 a49 = fifo[(i + 25) & 63];   // x[t+25]
      float2 d49 = fifo[(i + 40) & 63];   // x[t-24]

      float trx = sx7 * c7 + sx25 * c25 + sx49 * c49;
      float try_ = sy7 * c7 + sy25 * c25 + sy49 * c49;
      tp[0] = make_float2(trx, try_);
      rp[0] = make_float2(xv.x - trx, xv.y - try_);
      tp += C2;
      rp += C2;

      // Slide all three windows to center t+1.
      sx7  += a7.x  - d7.x;   sy7  += a7.y  - d7.y;
      sx25 += a25.x - d25.x;  sy25 += a25.y - d25.y;
      sx49 += a49.x - d49.x;  sy49 += a49.y - d49.y;
    }
  }
}

}  // namespace

extern "C" void kernel_launch(void* const* d_in, const int* in_sizes, int n_in,
                              void* d_out, int out_size, void* d_ws, size_t ws_size,
                              hipStream_t stream) {
  (void)in_sizes; (void)n_in; (void)out_size; (void)d_ws; (void)ws_size;

  const float2* x = (const float2*)d_in[0];
  float2* res = (float2*)d_out;                        // residual first
  float2* trend = res + (size_t)B * L * C2;            // then trend

  dim3 grid(L / CHUNK, 2, B);                          // (4, 2, 32) = 256 blocks
  series_decomp_kernel<<<grid, CPB, 0, stream>>>(x, res, trend);
}

// Round 6
// 125.734 us; speedup vs baseline: 3.0060x; 3.0060x over previous
//
#include <hip/hip_runtime.h>

// SeriesDecomp: trend = mean of moving averages (k = 7, 25, 49, replicate pad),
// residual = x - trend.  x: [32, 4096, 512] fp32.
// d_out = [residual | trend], each B*L*C floats.
//
// R6: R4's register-FIFO structure (proven, 159 us) + VEC=2 done right.
// R5's failure: 128-thread launch_bounds gave a 128-VGPR cap -> float2 FIFO
// spilled (WRITE_SIZE +112 MB). Now: 256 threads x float2 = all 512 channels,
// launch_bounds(256,2) -> 256-VGPR cap, FIFO(128)+overhead(~45) fits.
// dwordx2 halves VMEM instruction count vs R4. Nontemporal stores keep
// L2/L3 for the input (input is L3-resident across replays: R5 showed
// FETCH 178 MB < 268 MB input).

namespace {
constexpr int B = 32;
constexpr int L = 4096;
constexpr int C = 512;
constexpr int C2 = C / 2;          // 256 float2 groups per row
constexpr int CPB = 256;           // threads = float2 groups per block (all channels)
constexpr int CHUNK = 512;         // time steps per block
constexpr int BODY = 64;           // unrolled steps == FIFO depth
constexpr int NB = CHUNK / BODY;   // 8 outer iterations
constexpr int PF = 14;             // prefetch beyond t+25; span 50+14 = 64 exact

typedef float f32x2 __attribute__((ext_vector_type(2)));

__global__ __launch_bounds__(CPB, 2) void series_decomp_kernel(
    const f32x2* __restrict__ x,
    f32x2* __restrict__ res,
    f32x2* __restrict__ trend) {
  const int tid = threadIdx.x;     // 0..255 float2-group (= channel pair)
  const int chunk = blockIdx.x;    // 0..7
  const int b = blockIdx.y;        // 0..31
  const int t0 = chunk * CHUNK;    // multiple of 512 -> t0 & 63 == 0

  const size_t colbase = (size_t)b * L * C2 + tid;
  const f32x2* xp = x + colbase;

  f32x2 fifo[BODY];  // slot (r & 63) holds x[min(max(r,0),L-1)] (replicate)

  // Prologue: virtual rows t0-24 .. t0+38 -> slots (k+40)&63, k = 0..62.
  // Slot 39 is first written by step i=0 of the main body.
#pragma unroll
  for (int k = 0; k < BODY - 1; ++k) {
    int r = t0 - 24 + k;
    r = min(max(r, 0), L - 1);
    fifo[(k + 40) & 63] = xp[(size_t)r * C2];
  }

  // Initial window sums centered at t0 (virtual rows t0-24 .. t0+24).
  f32x2 s7 = {0.f, 0.f}, s25 = {0.f, 0.f}, s49 = {0.f, 0.f};
#pragma unroll
  for (int k = 0; k < 49; ++k) {
    f32x2 v = fifo[(k + 40) & 63];
    s49 += v;
    if (k >= 12 && k <= 36) s25 += v;   // rows t0-12..t0+12
    if (k >= 21 && k <= 27) s7  += v;   // rows t0-3 ..t0+3
  }

  // Folded coefficients: trend = s7/(7*3) + s25/(25*3) + s49/(49*3).
  const float c7 = 1.f / 21.f, c25 = 1.f / 75.f, c49 = 1.f / 147.f;

  f32x2* rp = res + colbase + (size_t)t0 * C2;
  f32x2* tp = trend + colbase + (size_t)t0 * C2;

  for (int g = 0; g < NB; ++g) {
    const int tb = t0 + g * BODY;  // tb & 63 == 0 -> slot(row r) = r & 63
#pragma unroll
    for (int i = 0; i < BODY; ++i) {
      // Prefetch virtual row tb+i+39 into slot (i+39)&63. Old content (row
      // t-25) was last read as d49 at step i-1 (WAR-safe); new value is first
      // read as a49 at step i+14 -> 14-step latency cover.
      {
        int r = min(tb + i + 25 + PF, L - 1);   // r >= 39 > 0 always
        fifo[(i + 25 + PF) & 63] = xp[(size_t)r * C2];
      }

      f32x2 xv  = fifo[i];               // x[t]
      f32x2 a7  = fifo[(i + 4)  & 63];   // x[t+4]
      f32x2 d7  = fifo[(i + 61) & 63];   // x[t-3]
      f32x2 a25 = fifo[(i + 13) & 63];   // x[t+13]
      f32x2 d25 = fifo[(i + 52) & 63];   // x[t-12]
      f32x2 a49 = fifo[(i + 25) & 63];   // x[t+25]
      f32x2 d49 = fifo[(i + 40) & 63];   // x[t-24]

      f32x2 tr = s7 * c7 + s25 * c25 + s49 * c49;
      __builtin_nontemporal_store(tr, tp);
      __builtin_nontemporal_store(xv - tr, rp);
      tp += C2;
      rp += C2;

      // Slide all three windows to center t+1.
      s7  += a7  - d7;
      s25 += a25 - d25;
      s49 += a49 - d49;
    }
  }
}

}  // namespace

extern "C" void kernel_launch(void* const* d_in, const int* in_sizes, int n_in,
                              void* d_out, int out_size, void* d_ws, size_t ws_size,
                              hipStream_t stream) {
  (void)in_sizes; (void)n_in; (void)out_size; (void)d_ws; (void)ws_size;

  const f32x2* x = (const f32x2*)d_in[0];
  f32x2* res = (f32x2*)d_out;                        // residual first
  f32x2* trend = res + (size_t)B * L * C2;           // then trend

  dim3 grid(L / CHUNK, B);                           // (8, 32) = 256 blocks
  series_decomp_kernel<<<grid, CPB, 0, stream>>>(x, res, trend);
}